// Round 2
// baseline (248.775 us; speedup 1.0000x reference)
//
#include <hip/hip_runtime.h>

#define SAMPLES 128
#define GRID_RES 128

typedef unsigned long long u64;

// Slab test replicating the reference op-for-op (no FMA contraction).
__device__ __forceinline__ void slab_test(
    float ox, float oy, float oz, float dx, float dy, float dz,
    float a0, float a1, float a2, float b0, float b1, float b2,
    float& tmin, float& tmax, float& dtv, bool& miss)
{
    float ix = __fdiv_rn(1.0f, dx);
    float iy = __fdiv_rn(1.0f, dy);
    float iz = __fdiv_rn(1.0f, dz);
    float t0x = __fmul_rn(__fsub_rn(a0, ox), ix);
    float t1x = __fmul_rn(__fsub_rn(b0, ox), ix);
    float t0y = __fmul_rn(__fsub_rn(a1, oy), iy);
    float t1y = __fmul_rn(__fsub_rn(b1, oy), iy);
    float t0z = __fmul_rn(__fsub_rn(a2, oz), iz);
    float t1z = __fmul_rn(__fsub_rn(b2, oz), iz);
    float tn = fmaxf(fmaxf(fminf(t0x, t1x), fminf(t0y, t1y)), fminf(t0z, t1z));
    float tf = fminf(fminf(fmaxf(t0x, t1x), fmaxf(t0y, t1y)), fmaxf(t0z, t1z));
    tn = fmaxf(tn, 0.0f);
    miss = (tf <= tn);
    tmin = miss ? 1e10f : fminf(tn, 1e10f);
    tmax = miss ? 1e10f : fminf(tf, 1e10f);
    dtv  = miss ? 0.0f : __fdiv_rn(__fsub_rn(tmax, tmin), (float)SAMPLES);
}

// Pass 1: one thread per (ray, sample). 256 threads = 2 rays/block.
// Wave w of the block covers exactly 64 consecutive samples of one ray,
// so __ballot gives one 64-bit occupancy mask word directly.
__global__ __launch_bounds__(256) void k_pass1(
    const float* __restrict__ ro, const float* __restrict__ rd,
    const float* __restrict__ aabb, const float* __restrict__ grid,
    float* __restrict__ out_tmin, float* __restrict__ out_tmax,
    u64* __restrict__ wmask, float* __restrict__ wtmin, float* __restrict__ wdt,
    int R)
{
    int tid = threadIdx.x;
    int ray = blockIdx.x * 2 + (tid >> 7);
    int s   = tid & 127;
    bool inr = (ray < R);

    bool miss = true;
    float tmin = 1e10f, tmax = 1e10f, dtv = 0.0f;
    float ox = 0.f, oy = 0.f, oz = 0.f, dx = 1.f, dy = 1.f, dz = 1.f;
    float a0 = 0.f, a1 = 0.f, a2 = 0.f, b0 = 1.f, b1 = 1.f, b2 = 1.f;
    if (inr) {
        ox = ro[3 * ray + 0]; oy = ro[3 * ray + 1]; oz = ro[3 * ray + 2];
        dx = rd[3 * ray + 0]; dy = rd[3 * ray + 1]; dz = rd[3 * ray + 2];
        a0 = aabb[0]; a1 = aabb[1]; a2 = aabb[2];
        b0 = aabb[3]; b1 = aabb[4]; b2 = aabb[5];
        slab_test(ox, oy, oz, dx, dy, dz, a0, a1, a2, b0, b1, b2,
                  tmin, tmax, dtv, miss);
    }

    bool valid = false;
    if (inr && !miss && dtv > 0.0f) {
        float fs    = (float)s;
        float start = __fadd_rn(tmin, __fmul_rn(fs, dtv));
        float end   = __fadd_rn(start, dtv);
        float tmid  = __fmul_rn(0.5f, __fadd_rn(start, end));
        float px = __fadd_rn(ox, __fmul_rn(dx, tmid));
        float py = __fadd_rn(oy, __fmul_rn(dy, tmid));
        float pz = __fadd_rn(oz, __fmul_rn(dz, tmid));
        float e0 = __fsub_rn(b0, a0);
        float e1 = __fsub_rn(b1, a1);
        float e2 = __fsub_rn(b2, a2);
        float ux = __fmul_rn(__fdiv_rn(__fsub_rn(px, a0), e0), (float)GRID_RES);
        float uy = __fmul_rn(__fdiv_rn(__fsub_rn(py, a1), e1), (float)GRID_RES);
        float uz = __fmul_rn(__fdiv_rn(__fsub_rn(pz, a2), e2), (float)GRID_RES);
        int cx = min(max((int)floorf(ux), 0), GRID_RES - 1);
        int cy = min(max((int)floorf(uy), 0), GRID_RES - 1);
        int cz = min(max((int)floorf(uz), 0), GRID_RES - 1);
        float g = grid[((cx * GRID_RES) + cy) * GRID_RES + cz];
        valid = (g > 0.5f);
    }

    u64 bmask = __ballot(valid);
    if (inr) {
        if (s == 0) {
            out_tmin[ray] = tmin;
            out_tmax[ray] = tmax;
            wtmin[ray] = tmin;
            wdt[ray] = dtv;
        }
        if ((tid & 63) == 0) {
            wmask[(size_t)ray * 2 + ((s >> 6) & 1)] = bmask;
        }
    }
}

// Pass 2: single-block exclusive scan of per-ray counts.
__global__ __launch_bounds__(1024) void k_scan(
    const u64* __restrict__ wmask, unsigned* __restrict__ wstart,
    unsigned* __restrict__ wtotal, float* __restrict__ info, int R)
{
    const int T = 1024;
    int t = threadIdx.x;
    int per = (R + T - 1) / T;
    int r0 = t * per;
    int r1 = min(r0 + per, R);

    unsigned sum = 0;
    for (int r = r0; r < r1; ++r)
        sum += (unsigned)__popcll(wmask[2 * r]) + (unsigned)__popcll(wmask[2 * r + 1]);

    __shared__ unsigned sd[T];
    sd[t] = sum;
    __syncthreads();
    for (int off = 1; off < T; off <<= 1) {
        unsigned v = (t >= off) ? sd[t - off] : 0u;
        __syncthreads();
        sd[t] += v;
        __syncthreads();
    }
    if (t == T - 1) *wtotal = sd[T - 1];

    unsigned run = sd[t] - sum;  // exclusive prefix for this thread's chunk
    for (int r = r0; r < r1; ++r) {
        unsigned c = (unsigned)__popcll(wmask[2 * r]) + (unsigned)__popcll(wmask[2 * r + 1]);
        wstart[r] = run;
        info[2 * r]     = (float)run;
        info[2 * r + 1] = (float)c;
        run += c;
    }
}

// Pass 3: every (ray, sample) thread writes exactly one 32B packed row.
// Valid -> compacted slot; invalid -> zero row in the tail. Bijective onto
// [0, total), so the whole packed buffer is rewritten every call.
__global__ __launch_bounds__(256) void k_pack(
    const float* __restrict__ ro, const float* __restrict__ rd,
    const u64* __restrict__ wmask, const unsigned* __restrict__ wstart,
    const float* __restrict__ wtmin, const float* __restrict__ wdt,
    const unsigned* __restrict__ wtotal,
    float* __restrict__ packed, int R)
{
    int gid = blockIdx.x * blockDim.x + threadIdx.x;
    if (gid >= R * SAMPLES) return;
    int ray = gid >> 7;
    int s   = gid & 127;

    u64 mlo = wmask[2 * ray];
    u64 mhi = wmask[2 * ray + 1];

    bool valid;
    unsigned below;
    if (s < 64) {   // wave-uniform branch (wave = 64 consecutive samples)
        valid = (mlo >> s) & 1ull;
        below = (unsigned)__popcll(mlo & ((1ull << s) - 1ull));
    } else {
        int s2 = s - 64;
        valid = (mhi >> s2) & 1ull;
        below = (unsigned)__popcll(mlo) +
                (unsigned)__popcll(mhi & ((1ull << s2) - 1ull));
    }

    unsigned vex = wstart[ray] + below;  // global # valid before this element
    unsigned row;
    float4 v0, v1;
    if (valid) {
        row = vex;
        float tmin = wtmin[ray];
        float dtv  = wdt[ray];
        float fs    = (float)s;
        float start = __fadd_rn(tmin, __fmul_rn(fs, dtv));
        float end   = __fadd_rn(start, dtv);
        v0 = make_float4(ro[3 * ray + 0], ro[3 * ray + 1], ro[3 * ray + 2],
                         rd[3 * ray + 0]);
        v1 = make_float4(rd[3 * ray + 1], rd[3 * ray + 2], start, end);
    } else {
        row = *wtotal + ((unsigned)gid - vex);
        v0 = make_float4(0.f, 0.f, 0.f, 0.f);
        v1 = v0;
    }
    float4* p = (float4*)(packed + (size_t)row * 8);
    p[0] = v0;
    p[1] = v1;
}

extern "C" void kernel_launch(void* const* d_in, const int* in_sizes, int n_in,
                              void* d_out, int out_size, void* d_ws, size_t ws_size,
                              hipStream_t stream)
{
    const float* ro   = (const float*)d_in[0];
    const float* rd   = (const float*)d_in[1];
    const float* aabb = (const float*)d_in[2];
    const float* grid = (const float*)d_in[3];
    // d_in[4] = num_samples (device scalar); S fixed at 128 per problem setup.

    int R = in_sizes[0] / 3;
    size_t total = (size_t)R * SAMPLES;

    float* out    = (float*)d_out;
    float* packed = out;                      // total*8
    float* info   = out + total * 8;          // 2R (ray_start, count) as floats
    float* otmin  = info + (size_t)2 * R;     // R
    float* otmax  = otmin + R;                // R

    char* w = (char*)d_ws;
    u64* wmask      = (u64*)w;                               // R*2 u64 = 16B/ray
    float* wtmin    = (float*)(w + (size_t)R * 16);          // R floats
    float* wdt      = wtmin + R;                             // R floats
    unsigned* wstart = (unsigned*)(wdt + R);                 // R u32
    unsigned* wtotal = wstart + R;                           // 1 u32

    int b1 = (R + 1) / 2;                     // 2 rays per 256-thread block
    k_pass1<<<b1, 256, 0, stream>>>(ro, rd, aabb, grid, otmin, otmax,
                                    wmask, wtmin, wdt, R);
    k_scan<<<1, 1024, 0, stream>>>(wmask, wstart, wtotal, info, R);
    int b3 = (int)((total + 255) / 256);
    k_pack<<<b3, 256, 0, stream>>>(ro, rd, wmask, wstart, wtmin, wdt, wtotal,
                                   packed, R);
}

// Round 3
// 92.981 us; speedup vs baseline: 2.6755x; 2.6755x over previous
//
#include <hip/hip_runtime.h>

#define SAMPLES 128
#define GRID_RES 128

typedef unsigned long long u64;

// Slab test replicating the reference op-for-op (no FMA contraction).
__device__ __forceinline__ void slab_test(
    float ox, float oy, float oz, float dx, float dy, float dz,
    float a0, float a1, float a2, float b0, float b1, float b2,
    float& tmin, float& tmax, float& dtv, bool& miss)
{
    float ix = __fdiv_rn(1.0f, dx);
    float iy = __fdiv_rn(1.0f, dy);
    float iz = __fdiv_rn(1.0f, dz);
    float t0x = __fmul_rn(__fsub_rn(a0, ox), ix);
    float t1x = __fmul_rn(__fsub_rn(b0, ox), ix);
    float t0y = __fmul_rn(__fsub_rn(a1, oy), iy);
    float t1y = __fmul_rn(__fsub_rn(b1, oy), iy);
    float t0z = __fmul_rn(__fsub_rn(a2, oz), iz);
    float t1z = __fmul_rn(__fsub_rn(b2, oz), iz);
    float tn = fmaxf(fmaxf(fminf(t0x, t1x), fminf(t0y, t1y)), fminf(t0z, t1z));
    float tf = fminf(fminf(fmaxf(t0x, t1x), fmaxf(t0y, t1y)), fmaxf(t0z, t1z));
    tn = fmaxf(tn, 0.0f);
    miss = (tf <= tn);
    tmin = miss ? 1e10f : fminf(tn, 1e10f);
    tmax = miss ? 1e10f : fminf(tf, 1e10f);
    dtv  = miss ? 0.0f : __fdiv_rn(__fsub_rn(tmax, tmin), (float)SAMPLES);
}

// Pass 1: one thread per (ray, sample). 256 threads = 2 rays/block.
// Wave = exactly 64 consecutive samples of one ray -> __ballot gives one
// 64-bit occupancy mask word directly.
__global__ __launch_bounds__(256) void k_pass1(
    const float* __restrict__ ro, const float* __restrict__ rd,
    const float* __restrict__ aabb, const float* __restrict__ grid,
    float* __restrict__ out_tmin, float* __restrict__ out_tmax,
    u64* __restrict__ wmask, float* __restrict__ wtmin, float* __restrict__ wdt,
    int R)
{
    int tid = threadIdx.x;
    int ray = blockIdx.x * 2 + (tid >> 7);
    int s   = tid & 127;
    bool inr = (ray < R);

    bool miss = true;
    float tmin = 1e10f, tmax = 1e10f, dtv = 0.0f;
    float ox = 0.f, oy = 0.f, oz = 0.f, dx = 1.f, dy = 1.f, dz = 1.f;
    float a0 = 0.f, a1 = 0.f, a2 = 0.f, b0 = 1.f, b1 = 1.f, b2 = 1.f;
    if (inr) {
        ox = ro[3 * ray + 0]; oy = ro[3 * ray + 1]; oz = ro[3 * ray + 2];
        dx = rd[3 * ray + 0]; dy = rd[3 * ray + 1]; dz = rd[3 * ray + 2];
        a0 = aabb[0]; a1 = aabb[1]; a2 = aabb[2];
        b0 = aabb[3]; b1 = aabb[4]; b2 = aabb[5];
        slab_test(ox, oy, oz, dx, dy, dz, a0, a1, a2, b0, b1, b2,
                  tmin, tmax, dtv, miss);
    }

    bool valid = false;
    if (inr && !miss && dtv > 0.0f) {
        float fs    = (float)s;
        float start = __fadd_rn(tmin, __fmul_rn(fs, dtv));
        float end   = __fadd_rn(start, dtv);
        float tmid  = __fmul_rn(0.5f, __fadd_rn(start, end));
        float px = __fadd_rn(ox, __fmul_rn(dx, tmid));
        float py = __fadd_rn(oy, __fmul_rn(dy, tmid));
        float pz = __fadd_rn(oz, __fmul_rn(dz, tmid));
        float e0 = __fsub_rn(b0, a0);
        float e1 = __fsub_rn(b1, a1);
        float e2 = __fsub_rn(b2, a2);
        float ux = __fmul_rn(__fdiv_rn(__fsub_rn(px, a0), e0), (float)GRID_RES);
        float uy = __fmul_rn(__fdiv_rn(__fsub_rn(py, a1), e1), (float)GRID_RES);
        float uz = __fmul_rn(__fdiv_rn(__fsub_rn(pz, a2), e2), (float)GRID_RES);
        int cx = min(max((int)floorf(ux), 0), GRID_RES - 1);
        int cy = min(max((int)floorf(uy), 0), GRID_RES - 1);
        int cz = min(max((int)floorf(uz), 0), GRID_RES - 1);
        float g = grid[((cx * GRID_RES) + cy) * GRID_RES + cz];
        valid = (g > 0.5f);
    }

    u64 bmask = __ballot(valid);
    if (inr) {
        if (s == 0) {
            out_tmin[ray] = tmin;
            out_tmax[ray] = tmax;
            wtmin[ray] = tmin;
            wdt[ray] = dtv;
        }
        if ((tid & 63) == 0) {
            wmask[(size_t)ray * 2 + ((s >> 6) & 1)] = bmask;
        }
    }
}

// Scan stage A: 1 ray per thread, 1024 threads/block. Wave shfl-scan +
// 16-wave LDS scan. Writes per-ray exclusive-in-block prefix and block sum.
__global__ __launch_bounds__(1024) void k_scanA(
    const u64* __restrict__ wmask, unsigned* __restrict__ lpre,
    unsigned* __restrict__ bsum, int R)
{
    int r    = blockIdx.x * 1024 + threadIdx.x;
    int lane = threadIdx.x & 63;
    int wv   = threadIdx.x >> 6;

    unsigned c = 0;
    if (r < R)
        c = (unsigned)__popcll(wmask[2 * r]) + (unsigned)__popcll(wmask[2 * r + 1]);

    unsigned inc = c;
    for (int o = 1; o < 64; o <<= 1) {
        unsigned v = __shfl_up(inc, o, 64);
        if (lane >= o) inc += v;
    }

    __shared__ unsigned sw[16];
    if (lane == 63) sw[wv] = inc;
    __syncthreads();
    if (wv == 0) {
        unsigned v = (lane < 16) ? sw[lane] : 0u;
        unsigned iv = v;
        for (int o = 1; o < 16; o <<= 1) {
            unsigned t2 = __shfl_up(iv, o, 64);
            if (lane >= o) iv += t2;
        }
        if (lane < 16) sw[lane] = iv - v;  // exclusive wave prefix
    }
    __syncthreads();

    unsigned excl = sw[wv] + (inc - c);
    if (r < R) lpre[r] = excl;
    if (threadIdx.x == 1023) bsum[blockIdx.x] = excl + c;  // block total
}

// Scan stage B: one wave scans the (<=64) block sums.
__global__ __launch_bounds__(64) void k_scanB(
    const unsigned* __restrict__ bsum, unsigned* __restrict__ boff,
    unsigned* __restrict__ wtotal, int nb)
{
    int t = threadIdx.x;
    unsigned v = (t < nb) ? bsum[t] : 0u;
    unsigned iv = v;
    for (int o = 1; o < 64; o <<= 1) {
        unsigned u = __shfl_up(iv, o, 64);
        if (t >= o) iv += u;
    }
    if (t < nb) boff[t] = iv - v;  // exclusive block offset
    if (t == 63) *wtotal = iv;     // grand total
}

// Pass 3: every (ray, sample) thread writes exactly one 32B packed row.
// Valid -> compacted slot; invalid -> zero row in the tail. Bijective onto
// [0, total), so the whole packed buffer is rewritten every call.
// s==0 thread per ray also writes packed_info.
__global__ __launch_bounds__(256) void k_pack(
    const float* __restrict__ ro, const float* __restrict__ rd,
    const u64* __restrict__ wmask,
    const unsigned* __restrict__ lpre, const unsigned* __restrict__ boff,
    const float* __restrict__ wtmin, const float* __restrict__ wdt,
    const unsigned* __restrict__ wtotal,
    float* __restrict__ packed, float* __restrict__ info, int R)
{
    int gid = blockIdx.x * blockDim.x + threadIdx.x;
    if (gid >= R * SAMPLES) return;
    int ray = gid >> 7;
    int s   = gid & 127;

    u64 mlo = wmask[2 * ray];
    u64 mhi = wmask[2 * ray + 1];
    unsigned wstart = boff[ray >> 10] + lpre[ray];

    if (s == 0) {
        unsigned cnt = (unsigned)__popcll(mlo) + (unsigned)__popcll(mhi);
        info[2 * ray]     = (float)wstart;
        info[2 * ray + 1] = (float)cnt;
    }

    bool valid;
    unsigned below;
    if (s < 64) {   // wave-uniform branch (wave = 64 consecutive samples)
        valid = (mlo >> s) & 1ull;
        below = (unsigned)__popcll(mlo & ((1ull << s) - 1ull));
    } else {
        int s2 = s - 64;
        valid = (mhi >> s2) & 1ull;
        below = (unsigned)__popcll(mlo) +
                (unsigned)__popcll(mhi & ((1ull << s2) - 1ull));
    }

    unsigned vex = wstart + below;  // global # valid before this element
    unsigned row;
    float4 v0, v1;
    if (valid) {
        row = vex;
        float tmin = wtmin[ray];
        float dtv  = wdt[ray];
        float fs    = (float)s;
        float start = __fadd_rn(tmin, __fmul_rn(fs, dtv));
        float end   = __fadd_rn(start, dtv);
        v0 = make_float4(ro[3 * ray + 0], ro[3 * ray + 1], ro[3 * ray + 2],
                         rd[3 * ray + 0]);
        v1 = make_float4(rd[3 * ray + 1], rd[3 * ray + 2], start, end);
    } else {
        row = *wtotal + ((unsigned)gid - vex);
        v0 = make_float4(0.f, 0.f, 0.f, 0.f);
        v1 = v0;
    }
    float4* p = (float4*)(packed + (size_t)row * 8);
    p[0] = v0;
    p[1] = v1;
}

extern "C" void kernel_launch(void* const* d_in, const int* in_sizes, int n_in,
                              void* d_out, int out_size, void* d_ws, size_t ws_size,
                              hipStream_t stream)
{
    const float* ro   = (const float*)d_in[0];
    const float* rd   = (const float*)d_in[1];
    const float* aabb = (const float*)d_in[2];
    const float* grid = (const float*)d_in[3];
    // d_in[4] = num_samples (device scalar); S fixed at 128 per problem setup.

    int R = in_sizes[0] / 3;
    size_t total = (size_t)R * SAMPLES;
    int nb = (R + 1023) / 1024;               // <= 64 for R = 65536

    float* out    = (float*)d_out;
    float* packed = out;                      // total*8
    float* info   = out + total * 8;          // 2R (ray_start, count) as floats
    float* otmin  = info + (size_t)2 * R;     // R
    float* otmax  = otmin + R;                // R

    char* w = (char*)d_ws;
    u64* wmask       = (u64*)w;                              // R*2 u64
    float* wtmin     = (float*)(w + (size_t)R * 16);         // R floats
    float* wdt       = wtmin + R;                            // R floats
    unsigned* lpre   = (unsigned*)(wdt + R);                 // R u32
    unsigned* bsum   = lpre + R;                             // nb u32
    unsigned* boff   = bsum + 64;                            // nb u32
    unsigned* wtotal = boff + 64;                            // 1 u32

    int b1 = (R + 1) / 2;                     // 2 rays per 256-thread block
    k_pass1<<<b1, 256, 0, stream>>>(ro, rd, aabb, grid, otmin, otmax,
                                    wmask, wtmin, wdt, R);
    k_scanA<<<nb, 1024, 0, stream>>>(wmask, lpre, bsum, R);
    k_scanB<<<1, 64, 0, stream>>>(bsum, boff, wtotal, nb);
    int b3 = (int)((total + 255) / 256);
    k_pack<<<b3, 256, 0, stream>>>(ro, rd, wmask, lpre, boff, wtmin, wdt,
                                   wtotal, packed, info, R);
}